// Round 10
// baseline (48390.170 us; speedup 1.0000x reference)
//
#include <hip/hip_runtime.h>

// RNN_85117661872189 on gfx950 — round 10: 256-thread k_rec, 2 rows/thread,
// 512-reg/wave budget (amdgpu_waves_per_eu(1,1)) so weights truly fit in VGPRs.
// Rounds 6-9: 512-thr blocks cap regs at 256/wave -> allocator remats weights
// from L2 every step (FETCH 5.5MB/step, VALUBusy 41%). This round removes the
// structural cap instead of fighting the allocator.
// d_in[0] input_seq [2048][128] i32; f32: emb[128][128], Wxh_w[512][128],
// Wxh_b[512], Whh_w[512][512], Whh_b[512], dec_w[128][512], dec_b[128].
// Output f32 [2048][128][128].

#define TT 2048
#define BB 128
#define HH 512
#define OO 128
#define MAGIC 123456.0f
#define NVG 51   // u32x4 groups per row in VGPR (groups 0..50)
#define NLG 13   // u32x4 groups per row in LDS  (groups 51..63)

typedef _Float16 h2_t __attribute__((ext_vector_type(2)));
typedef unsigned int u32x4 __attribute__((ext_vector_type(4)));
union UF { unsigned int u; float f; h2_t h; unsigned short us[2]; };

__device__ __forceinline__ unsigned int packf16(float a, float b) {
  UF r; r.h[0] = (_Float16)a; r.h[1] = (_Float16)b; return r.u;
}
__device__ __forceinline__ float dot2a(unsigned int a, unsigned int b, float c) {
  UF x, y; x.u = a; y.u = b;
#if __has_builtin(__builtin_amdgcn_fdot2)
  return __builtin_amdgcn_fdot2(x.h, y.h, c, false);   // v_dot2_f32_f16
#else
  return fmaf((float)x.h[1], (float)y.h[1], fmaf((float)x.h[0], (float)y.h[0], c));
#endif
}
__device__ __forceinline__ unsigned short f16bits(float x) {
  UF r; r.h[0] = (_Float16)x; r.h[1] = (_Float16)0.f; return r.us[0];
}
__device__ __forceinline__ float tanh_fast(float x) {  // x pre-clamped
  float e = __expf(2.0f * x);
  return 1.0f - 2.0f / (e + 1.0f);
}
__device__ __forceinline__ float sanz(float x) {  // non-finite -> 0 (probe-readable)
  return (x >= -1e20f && x <= 1e20f) ? x : 0.f;
}
__device__ __forceinline__ unsigned int rdlane(unsigned int v, int l) {
#if __has_builtin(__builtin_amdgcn_readlane)
  return (unsigned int)__builtin_amdgcn_readlane((int)v, l);
#else
  return (unsigned int)__shfl((int)v, l, 64);
#endif
}

// ---- k_init: zero probe markers ----
extern "C" __global__ void k_init(float* __restrict__ mk) {
  if (threadIdx.x < 8) mk[threadIdx.x] = 0.f;
}

// ---- k_pre: P[id][j] = emb[id]·Wxh_w[j] + Wxh_b[j] + Whh_b[j] (f32) ----
extern "C" __global__ __launch_bounds__(512)
void k_pre(const float* __restrict__ emb, const float* __restrict__ wxh,
           const float* __restrict__ bxh, const float* __restrict__ bhh,
           float* __restrict__ P, float* __restrict__ mk) {
  const int id = blockIdx.x;
  const int j = threadIdx.x;
  const float4* er = (const float4*)(emb + id * 128);
  const float4* wr = (const float4*)(wxh + j * 128);
  float acc = 0.f;
  #pragma unroll
  for (int c = 0; c < 32; ++c) {
    const float4 e = er[c], w = wr[c];
    acc = fmaf(e.x, w.x, fmaf(e.y, w.y, fmaf(e.z, w.z, fmaf(e.w, w.w, acc))));
  }
  P[id * HH + j] = acc + bxh[j] + bhh[j];
  if (id == 0 && j == 0) mk[0] = MAGIC;
}

// ---- k_pack: Whh f32 [512][512] -> f16 pair-dwords wpack[row][256] ----
extern "C" __global__ __launch_bounds__(256)
void k_pack(const float* __restrict__ whh, unsigned int* __restrict__ wpack) {
  const int row = blockIdx.x;      // 0..511
  const int pd = threadIdx.x;      // 0..255
  const float2 w = *(const float2*)(whh + row * 512 + 2 * pd);
  wpack[row * 256 + pd] = packf16(w.x, w.y);
}

// ---- k_packd: decP4[c4*128+o] = f16 pairs of dec_w[o][8c4..8c4+7] ----
extern "C" __global__ __launch_bounds__(256)
void k_packd(const float* __restrict__ dw, uint4* __restrict__ decP4) {
  const int id = blockIdx.x * 256 + threadIdx.x;   // 0..8191
  const int c4 = id >> 7, o = id & 127;
  const float* src = dw + o * 512 + 8 * c4;
  uint4 v;
  v.x = packf16(src[0], src[1]);
  v.y = packf16(src[2], src[3]);
  v.z = packf16(src[4], src[5]);
  v.w = packf16(src[6], src[7]);
  decP4[id] = v;
}

// group g covers pair-dwords 4g..4g+3 (= h cols 8g..8g+7); lane g of the wave
// holds exactly those 4 h pair-dwords in hv (numerically verified r6-r9).
// One readlane quad feeds BOTH rows' dot2s.
#define GSTEP2(WA, WB, g)                               \
  {                                                     \
    const unsigned int bc0 = rdlane(hv.x, (g));         \
    const unsigned int bc1 = rdlane(hv.y, (g));         \
    const unsigned int bc2 = rdlane(hv.z, (g));         \
    const unsigned int bc3 = rdlane(hv.w, (g));         \
    aA0 = dot2a((WA).x, bc0, aA0);                      \
    aA1 = dot2a((WA).y, bc1, aA1);                      \
    aA2 = dot2a((WA).z, bc2, aA2);                      \
    aA3 = dot2a((WA).w, bc3, aA3);                      \
    aB0 = dot2a((WB).x, bc0, aB0);                      \
    aB1 = dot2a((WB).y, bc1, aB1);                      \
    aB2 = dot2a((WB).z, bc2, aB2);                      \
    aB3 = dot2a((WB).w, bc3, aB3);                      \
  }

#define WLIST(X) \
  X(0) X(1) X(2) X(3) X(4) X(5) X(6) X(7) X(8) X(9) \
  X(10) X(11) X(12) X(13) X(14) X(15) X(16) X(17) X(18) X(19) \
  X(20) X(21) X(22) X(23) X(24) X(25) X(26) X(27) X(28) X(29) \
  X(30) X(31) X(32) X(33) X(34) X(35) X(36) X(37) X(38) X(39) \
  X(40) X(41) X(42) X(43) X(44) X(45) X(46) X(47) X(48) X(49) X(50)
#define LOADA(i) u32x4 a_##i = wpA[i];
#define LOADB(i) u32x4 b_##i = wpB[i];
#define USEAB(i) GSTEP2(a_##i, b_##i, i)

// ---- k_rec: 2048 steps; one WG (256 thr, 4 waves) per batch row;
//      thread owns Whh rows tid and tid+256 ----
extern "C" __global__
__attribute__((amdgpu_flat_work_group_size(256, 256), amdgpu_waves_per_eu(1, 1)))
void k_rec(const int* __restrict__ idx, const float* __restrict__ P,
           const unsigned int* __restrict__ wpack,
           float* __restrict__ hstate, unsigned short* __restrict__ ring16,
           float* __restrict__ mk, int t0, int nT) {
  extern __shared__ __align__(16) unsigned char smem[];
  u32x4* wl4 = (u32x4*)smem;                                  // [2*NLG][256] 106,496 B
  unsigned short* hb16 = (unsigned short*)(smem + 2 * NLG * 256 * 16);  // [2][512]
  const uint4* hb4 = (const uint4*)hb16;                      // 64 uint4 per buffer
  const int tid = threadIdx.x;                                // 0..255
  const int b = blockIdx.x;
  const int lane = tid & 63;
  if (t0 == 0 && b == 0 && tid == 0) mk[1] = MAGIC;

  const u32x4* wpA = (const u32x4*)wpack + (size_t)tid * 64;          // row tid
  const u32x4* wpB = (const u32x4*)wpack + ((size_t)tid + 256) * 64;  // row tid+256
  WLIST(LOADA)                               // 51 u32x4 = 204 dwords (row A)
  WLIST(LOADB)                               // 51 u32x4 = 204 dwords (row B)
  #pragma unroll
  for (int s = 0; s < NLG; ++s) {            // groups 51..63 of each row -> LDS
    wl4[s * 256 + tid] = wpA[NVG + s];
    wl4[(NLG + s) * 256 + tid] = wpB[NVG + s];
  }

  const float h0A = (t0 == 0) ? 0.f : hstate[b * HH + tid];
  const float h0B = (t0 == 0) ? 0.f : hstate[b * HH + tid + 256];
  hb16[tid] = f16bits(h0A);
  hb16[tid + 256] = f16bits(h0B);
  float hlastA = h0A, hlastB = h0B;
  __syncthreads();

  for (int tl = 0; tl < nT; ++tl) {
    const int rb = tl & 1, wb = rb ^ 1;
    const int id = idx[(t0 + tl) * BB + b];  // wave-uniform -> s_load
    const float pjA = P[id * HH + tid];
    const float pjB = P[id * HH + tid + 256];
    const uint4 hv = hb4[rb * 64 + lane];    // lane's 4 h pair-dwords
    float aA0 = 0.f, aA1 = 0.f, aA2 = 0.f, aA3 = 0.f;
    float aB0 = 0.f, aB1 = 0.f, aB2 = 0.f, aB3 = 0.f;
    #pragma unroll
    for (int s = 0; s < NLG; ++s) {          // LDS groups first (ds_reads issue early)
      const u32x4 wa = wl4[s * 256 + tid];
      const u32x4 wc = wl4[(NLG + s) * 256 + tid];
      GSTEP2(wa, wc, NVG + s);
    }
    WLIST(USEAB)                             // VGPR-resident groups
    float sA = aA0 + aA1 + aA2 + aA3 + pjA;
    float sB = aB0 + aB1 + aB2 + aB3 + pjB;
    sA = fminf(fmaxf(sA, -30.f), 30.f);      // IEEE min/max drop NaN
    sB = fminf(fmaxf(sB, -30.f), 30.f);
    const float hA = tanh_fast(sA);
    const float hB = tanh_fast(sB);
    const unsigned short h16A = f16bits(hA);
    const unsigned short h16B = f16bits(hB);
    hb16[wb * 512 + tid] = h16A;
    hb16[wb * 512 + tid + 256] = h16B;
    const size_t ro = ((size_t)tl * BB + b) * HH + tid;
    ring16[ro] = h16A;
    ring16[ro + 256] = h16B;
    hlastA = hA; hlastB = hB;
    __syncthreads();                         // h[wb] visible for next step
  }
  hstate[b * HH + tid] = hlastA;
  hstate[b * HH + tid + 256] = hlastB;
  if (t0 == 0 && b == 0 && tid == 0) mk[2] = MAGIC;
}

// ---- k_dec: out rows = ring(f16) · decP + dec_b; 64 rows x 128 o per block ----
extern "C" __global__ __launch_bounds__(512)
void k_dec(const uint4* __restrict__ ring4, const uint4* __restrict__ decP4,
           const float* __restrict__ decb, float* __restrict__ out,
           float* __restrict__ mk, int t0) {
  extern __shared__ __align__(16) unsigned char smem[];
  uint4* hl4 = (uint4*)smem;                  // [64 rows][64 c4] = 65,536 B
  const int tid = threadIdx.x;
  const size_t r0 = (size_t)blockIdx.x * 64;
  #pragma unroll
  for (int i = 0; i < 8; ++i) {               // 64x512 f16 h tile, coalesced
    const int u = i * 512 + tid;
    hl4[u] = ring4[(r0 + (u >> 6)) * 64 + (u & 63)];
  }
  __syncthreads();
  const int oq = tid & 31, tq = tid >> 5;     // o in {oq+32r}, row in {tq+16s}
  float acc[4][4];
  #pragma unroll
  for (int r = 0; r < 4; ++r)
    #pragma unroll
    for (int s = 0; s < 4; ++s) acc[r][s] = 0.f;
  #pragma unroll 2
  for (int c4 = 0; c4 < 64; ++c4) {
    uint4 h4[4], d4[4];
    #pragma unroll
    for (int s = 0; s < 4; ++s) h4[s] = hl4[(tq + 16 * s) * 64 + c4];
    #pragma unroll
    for (int r = 0; r < 4; ++r) d4[r] = decP4[c4 * 128 + oq + 32 * r];
    #pragma unroll
    for (int r = 0; r < 4; ++r)
      #pragma unroll
      for (int s = 0; s < 4; ++s) {
        acc[r][s] = dot2a(d4[r].x, h4[s].x, acc[r][s]);
        acc[r][s] = dot2a(d4[r].y, h4[s].y, acc[r][s]);
        acc[r][s] = dot2a(d4[r].z, h4[s].z, acc[r][s]);
        acc[r][s] = dot2a(d4[r].w, h4[s].w, acc[r][s]);
      }
  }
  #pragma unroll
  for (int r = 0; r < 4; ++r) {
    const float db = decb[oq + 32 * r];
    #pragma unroll
    for (int s = 0; s < 4; ++s) {
      const size_t g = r0 + tq + 16 * s;
      out[((size_t)t0 * BB + g) * OO + oq + 32 * r] = sanz(acc[r][s] + db);
    }
  }
  if (t0 == 0 && blockIdx.x == 0 && tid == 0) mk[3] = MAGIC;
}

// ---- k_probe: first missing stage -> readable code in out[0] ----
extern "C" __global__ void k_probe(const float* __restrict__ mk, float* __restrict__ out,
                                   int wsTooSmall) {
  if (wsTooSmall)     { out[0] = 100000.f; return; }
  if (mk[0] != MAGIC) { out[0] = 200000.f; return; }
  if (mk[1] != MAGIC) { out[0] = 300000.f; return; }
  if (mk[2] != MAGIC) { out[0] = 400000.f; return; }
  if (mk[3] != MAGIC) { out[0] = 500000.f; return; }
}

extern "C" void kernel_launch(void* const* d_in, const int* in_sizes, int n_in,
                              void* d_out, int out_size, void* d_ws, size_t ws_size,
                              hipStream_t stream) {
  (void)in_sizes; (void)n_in; (void)out_size;
  const int* idx = (const int*)d_in[0];
  const float* emb = (const float*)d_in[1];
  const float* wxh = (const float*)d_in[2];
  const float* bxh = (const float*)d_in[3];
  const float* whh = (const float*)d_in[4];
  const float* bhh = (const float*)d_in[5];
  const float* dw  = (const float*)d_in[6];
  const float* db  = (const float*)d_in[7];
  float* out = (float*)d_out;

  char* ws = (char*)d_ws;
  float* P = (float*)ws;                                    // @0       256 KB
  float* hstate = (float*)(ws + (256 << 10));               // @256 KB  256 KB
  float* mk = (float*)(ws + (512 << 10));                   // @512 KB    4 KB
  unsigned int* wpack = (unsigned int*)(ws + (516 << 10));  // @516 KB  512 KB
  uint4* decP4 = (uint4*)(ws + (1076 << 10));               // @1076 KB 128 KB
  unsigned short* ring16 = (unsigned short*)(ws + (1204 << 10));  // @1204 KB

  int chunkT = 0;
  const int opts[8] = {2048, 1024, 768, 512, 256, 128, 32, 8};
  for (int i = 0; i < 8; ++i) {
    const size_t need = (size_t)(1204 << 10) + (size_t)opts[i] * BB * HH * 2;
    if (ws_size >= need) { chunkT = opts[i]; break; }
  }
  if (chunkT == 0) {
    k_probe<<<1, 1, 0, stream>>>(nullptr, out, 1);
    return;
  }

  const int ldsRec = 2 * NLG * 256 * 16 + 2048;  // 108,544 B
  const int ldsDec = 64 * 64 * 16;               //  65,536 B
  (void)hipFuncSetAttribute(reinterpret_cast<const void*>(k_rec),
                            hipFuncAttributeMaxDynamicSharedMemorySize, ldsRec);
  (void)hipFuncSetAttribute(reinterpret_cast<const void*>(k_dec),
                            hipFuncAttributeMaxDynamicSharedMemorySize, ldsDec);

  k_init<<<1, 64, 0, stream>>>(mk);
  k_pre<<<128, 512, 0, stream>>>(emb, wxh, bxh, bhh, P, mk);
  k_pack<<<512, 256, 0, stream>>>(whh, wpack);
  k_packd<<<32, 256, 0, stream>>>(dw, decP4);
  for (int t0 = 0; t0 < TT; t0 += chunkT) {
    k_rec<<<BB, 256, ldsRec, stream>>>(idx, P, wpack, hstate, ring16, mk, t0, chunkT);
    k_dec<<<chunkT * 2, 512, ldsDec, stream>>>((const uint4*)ring16, decP4, db, out, mk, t0);
  }
  k_probe<<<1, 1, 0, stream>>>(mk, out, 0);
}

// Round 13
// 4953.485 us; speedup vs baseline: 9.7689x; 9.7689x over previous
//
#include <hip/hip_runtime.h>

// RNN_85117661872189 on gfx950 — round 13: compiler-emitted verified math +
// non-rematerializable weights.
// r12 probe isolated the asm bug to the dot path; r7 verified the same math in
// C++. Root cause of r6-9 slowness: ordinary weight loads are legally re-loaded
// each step by the register allocator. Fix: weights enter via asm-volatile
// "=&v" outputs (cannot be re-executed) -> allocator must keep 184 dwords in
// VGPRs (budget 256 @ waves_per_eu(2,2)). Inner loop = r7's verified GSTEP.
// d_in[0] input_seq [2048][128] i32; f32: emb[128][128], Wxh_w[512][128],
// Wxh_b[512], Whh_w[512][512], Whh_b[512], dec_w[128][512], dec_b[128].
// Output f32 [2048][128][128].

#define TT 2048
#define BB 128
#define HH 512
#define OO 128
#define MAGIC 123456.0f
#define NLDG 18   // u32x4 weight groups in LDS (groups 46..63)

typedef _Float16 h2_t __attribute__((ext_vector_type(2)));
typedef unsigned int u32x4 __attribute__((ext_vector_type(4)));
union UF { unsigned int u; float f; h2_t h; unsigned short us[2]; };

__device__ __forceinline__ unsigned int packf16(float a, float b) {
  UF r; r.h[0] = (_Float16)a; r.h[1] = (_Float16)b; return r.u;
}
__device__ __forceinline__ float dot2a(unsigned int a, unsigned int b, float c) {
  UF x, y; x.u = a; y.u = b;
#if __has_builtin(__builtin_amdgcn_fdot2)
  return __builtin_amdgcn_fdot2(x.h, y.h, c, false);   // v_dot2_f32_f16
#else
  return fmaf((float)x.h[1], (float)y.h[1], fmaf((float)x.h[0], (float)y.h[0], c));
#endif
}
__device__ __forceinline__ unsigned short f16bits(float x) {
  UF r; r.h[0] = (_Float16)x; r.h[1] = (_Float16)0.f; return r.us[0];
}
__device__ __forceinline__ float f16tof(unsigned short u) {
  UF r; r.us[0] = u; r.us[1] = 0; return (float)r.h[0];
}
__device__ __forceinline__ float tanh_fast(float x) {  // x pre-clamped
  float e = __expf(2.0f * x);
  return 1.0f - 2.0f / (e + 1.0f);
}
__device__ __forceinline__ float sanz(float x) {
  return (x >= -1e20f && x <= 1e20f) ? x : 0.f;
}
__device__ __forceinline__ unsigned int rdlane(unsigned int v, int l) {
#if __has_builtin(__builtin_amdgcn_readlane)
  return (unsigned int)__builtin_amdgcn_readlane((int)v, l);
#else
  return (unsigned int)__shfl((int)v, l, 64);
#endif
}

// ---- k_init / k_pre / k_pack / k_packd (unchanged, proven) ----
extern "C" __global__ void k_init(float* __restrict__ mk) {
  if (threadIdx.x < 8) mk[threadIdx.x] = 0.f;
}

extern "C" __global__ __launch_bounds__(512)
void k_pre(const float* __restrict__ emb, const float* __restrict__ wxh,
           const float* __restrict__ bxh, const float* __restrict__ bhh,
           float* __restrict__ P, float* __restrict__ mk) {
  const int id = blockIdx.x;
  const int j = threadIdx.x;
  const float4* er = (const float4*)(emb + id * 128);
  const float4* wr = (const float4*)(wxh + j * 128);
  float acc = 0.f;
  #pragma unroll
  for (int c = 0; c < 32; ++c) {
    const float4 e = er[c], w = wr[c];
    acc = fmaf(e.x, w.x, fmaf(e.y, w.y, fmaf(e.z, w.z, fmaf(e.w, w.w, acc))));
  }
  P[id * HH + j] = acc + bxh[j] + bhh[j];
  if (id == 0 && j == 0) mk[0] = MAGIC;
}

extern "C" __global__ __launch_bounds__(256)
void k_pack(const float* __restrict__ whh, unsigned int* __restrict__ wpack) {
  const int row = blockIdx.x;
  const int pd = threadIdx.x;
  const float2 w = *(const float2*)(whh + row * 512 + 2 * pd);
  wpack[row * 256 + pd] = packf16(w.x, w.y);
}

extern "C" __global__ __launch_bounds__(256)
void k_packd(const float* __restrict__ dw, uint4* __restrict__ decP4) {
  const int id = blockIdx.x * 256 + threadIdx.x;
  const int c4 = id >> 7, o = id & 127;
  const float* src = dw + o * 512 + 8 * c4;
  uint4 v;
  v.x = packf16(src[0], src[1]);
  v.y = packf16(src[2], src[3]);
  v.z = packf16(src[4], src[5]);
  v.w = packf16(src[6], src[7]);
  decP4[id] = v;
}

// Weight-residency loaders: values are asm outputs -> cannot be rematerialized.
#define LOADBLK7(PTR, W0, W1, W2, W3, W4, W5, W6)             \
  asm volatile(                                               \
    "global_load_dwordx4 %0, %7, off\n\t"                     \
    "global_load_dwordx4 %1, %7, off offset:16\n\t"           \
    "global_load_dwordx4 %2, %7, off offset:32\n\t"           \
    "global_load_dwordx4 %3, %7, off offset:48\n\t"           \
    "global_load_dwordx4 %4, %7, off offset:64\n\t"           \
    "global_load_dwordx4 %5, %7, off offset:80\n\t"           \
    "global_load_dwordx4 %6, %7, off offset:96\n\t"           \
    "s_waitcnt vmcnt(0)"                                      \
    : "=&v"(W0), "=&v"(W1), "=&v"(W2), "=&v"(W3),             \
      "=&v"(W4), "=&v"(W5), "=&v"(W6)                         \
    : "v"(PTR))
#define LOADBLK4(PTR, W0, W1, W2, W3)                         \
  asm volatile(                                               \
    "global_load_dwordx4 %0, %4, off\n\t"                     \
    "global_load_dwordx4 %1, %4, off offset:16\n\t"           \
    "global_load_dwordx4 %2, %4, off offset:32\n\t"           \
    "global_load_dwordx4 %3, %4, off offset:48\n\t"           \
    "s_waitcnt vmcnt(0)"                                      \
    : "=&v"(W0), "=&v"(W1), "=&v"(W2), "=&v"(W3)              \
    : "v"(PTR))

// group g covers pair-dwords 4g..4g+3; lane g holds them in hv (verified r7).
#define GSTEP(W4, g)                                    \
  {                                                     \
    a0 = dot2a((W4).x, rdlane(hv.x, (g)), a0);          \
    a1 = dot2a((W4).y, rdlane(hv.y, (g)), a1);          \
    a2 = dot2a((W4).z, rdlane(hv.z, (g)), a2);          \
    a3 = dot2a((W4).w, rdlane(hv.w, (g)), a3);          \
  }

#define WL(X) \
  X(0) X(1) X(2) X(3) X(4) X(5) X(6) X(7) X(8) X(9) \
  X(10) X(11) X(12) X(13) X(14) X(15) X(16) X(17) X(18) X(19) \
  X(20) X(21) X(22) X(23) X(24) X(25) X(26) X(27) X(28) X(29) \
  X(30) X(31) X(32) X(33) X(34) X(35) X(36) X(37) X(38) X(39) \
  X(40) X(41) X(42) X(43) X(44) X(45)
#define DECLW(i) u32x4 w_##i;
#define USEW(i) GSTEP(w_##i, i)

// ---- k_rec: 2048 steps; one WG (512 thr) per batch row; thread = one h-row ----
extern "C" __global__
__attribute__((amdgpu_flat_work_group_size(512, 512), amdgpu_waves_per_eu(2, 2)))
void k_rec(const int* __restrict__ idx, const float* __restrict__ P,
           const unsigned int* __restrict__ wpack,
           float* __restrict__ hstate, unsigned short* __restrict__ ring16,
           float* __restrict__ mk, int t0, int nT) {
  extern __shared__ __align__(16) unsigned char smem[];
  u32x4* wl4 = (u32x4*)smem;                                   // [NLDG][512] 147,456 B
  unsigned short* hb16 = (unsigned short*)(smem + NLDG * 512 * 16);  // [2][512]
  const uint4* hb4 = (const uint4*)hb16;
  const int tid = threadIdx.x;
  const int b = blockIdx.x;
  const int lane = tid & 63;
  if (t0 == 0 && b == 0 && tid == 0) mk[1] = MAGIC;

  const u32x4* wp = (const u32x4*)(wpack + (size_t)tid * 256);
  #pragma unroll
  for (int s = 0; s < NLDG; ++s) wl4[s * 512 + tid] = wp[46 + s];  // groups 46..63

  WL(DECLW)                                    // 46 u32x4 = 184 dwords
  LOADBLK7(wp +  0, w_0,  w_1,  w_2,  w_3,  w_4,  w_5,  w_6);
  LOADBLK7(wp +  7, w_7,  w_8,  w_9,  w_10, w_11, w_12, w_13);
  LOADBLK7(wp + 14, w_14, w_15, w_16, w_17, w_18, w_19, w_20);
  LOADBLK7(wp + 21, w_21, w_22, w_23, w_24, w_25, w_26, w_27);
  LOADBLK7(wp + 28, w_28, w_29, w_30, w_31, w_32, w_33, w_34);
  LOADBLK7(wp + 35, w_35, w_36, w_37, w_38, w_39, w_40, w_41);
  LOADBLK4(wp + 42, w_42, w_43, w_44, w_45);

  const float h0 = (t0 == 0) ? 0.f : hstate[b * HH + tid];
  hb16[tid] = f16bits(h0);
  float hlast = h0;
  __syncthreads();

  for (int tl = 0; tl < nT; ++tl) {
    const int rb = tl & 1, wb = rb ^ 1;
    const int id = idx[(t0 + tl) * BB + b];    // wave-uniform
    const float pj = P[id * HH + tid];
    const uint4 hv = hb4[rb * 64 + lane];      // lane's 4 h pair-dwords
    float a0 = 0.f, a1 = 0.f, a2 = 0.f, a3 = 0.f;
    #pragma unroll
    for (int s = 0; s < NLDG; ++s) {           // LDS groups (ds_reads issue early)
      const u32x4 w4 = wl4[s * 512 + tid];     // conflict-free b128
      GSTEP(w4, 46 + s);
    }
    WL(USEW)                                   // VGPR-resident groups 0..45
    float s = a0 + a1 + a2 + a3 + pj;
    s = fminf(fmaxf(s, -30.f), 30.f);          // IEEE min/max drop NaN
    const float hvf = tanh_fast(s);
    const unsigned short h16 = f16bits(hvf);
    hb16[wb * 512 + tid] = h16;
    ring16[((size_t)tl * BB + b) * HH + tid] = h16;
    hlast = hvf;
    __syncthreads();                           // h[wb] visible for next step
  }
  hstate[b * HH + tid] = hlast;
  if (t0 == 0 && b == 0 && tid == 0) mk[2] = MAGIC;
}

// ---- k_chk: recompute steps 0/1 for b=0 in plain HIP; flag mismatches ----
extern "C" __global__ __launch_bounds__(512)
void k_chk(const int* __restrict__ idx, const float* __restrict__ P,
           const unsigned int* __restrict__ wpack,
           const unsigned short* __restrict__ ring16, float* __restrict__ mk) {
  __shared__ unsigned short h1s[512];
  const int j = threadIdx.x;
  h1s[j] = ring16[j];
  __syncthreads();
  {
    const float pj = P[idx[0] * HH + j];
    const float s = fminf(fmaxf(pj, -30.f), 30.f);
    const float d = fabsf(f16tof(h1s[j]) - f16tof(f16bits(tanh_fast(s))));
    if (d > 0.02f) mk[5] = 7.f;
  }
  {
    const unsigned int* wr = wpack + (size_t)j * 256;
    const unsigned int* hp = (const unsigned int*)h1s;
    float a0 = 0.f, a1 = 0.f, a2 = 0.f, a3 = 0.f;
    for (int g = 0; g < 64; ++g) {
      a0 = dot2a(wr[4 * g + 0], hp[4 * g + 0], a0);
      a1 = dot2a(wr[4 * g + 1], hp[4 * g + 1], a1);
      a2 = dot2a(wr[4 * g + 2], hp[4 * g + 2], a2);
      a3 = dot2a(wr[4 * g + 3], hp[4 * g + 3], a3);
    }
    const float pj = P[idx[BB] * HH + j];
    const float s = fminf(fmaxf((a0 + a1) + (a2 + a3) + pj, -30.f), 30.f);
    const float d = fabsf(f16tof(ring16[BB * HH + j]) - f16tof(f16bits(tanh_fast(s))));
    if (d > 0.02f) mk[4] = 7.f;
  }
}

// ---- k_dec: out rows = ring(f16) · decP + dec_b (unchanged) ----
extern "C" __global__ __launch_bounds__(512)
void k_dec(const uint4* __restrict__ ring4, const uint4* __restrict__ decP4,
           const float* __restrict__ decb, float* __restrict__ out,
           float* __restrict__ mk, int t0) {
  extern __shared__ __align__(16) unsigned char smem[];
  uint4* hl4 = (uint4*)smem;
  const int tid = threadIdx.x;
  const size_t r0 = (size_t)blockIdx.x * 64;
  #pragma unroll
  for (int i = 0; i < 8; ++i) {
    const int u = i * 512 + tid;
    hl4[u] = ring4[(r0 + (u >> 6)) * 64 + (u & 63)];
  }
  __syncthreads();
  const int oq = tid & 31, tq = tid >> 5;
  float acc[4][4];
  #pragma unroll
  for (int r = 0; r < 4; ++r)
    #pragma unroll
    for (int s = 0; s < 4; ++s) acc[r][s] = 0.f;
  #pragma unroll 2
  for (int c4 = 0; c4 < 64; ++c4) {
    uint4 h4[4], d4[4];
    #pragma unroll
    for (int s = 0; s < 4; ++s) h4[s] = hl4[(tq + 16 * s) * 64 + c4];
    #pragma unroll
    for (int r = 0; r < 4; ++r) d4[r] = decP4[c4 * 128 + oq + 32 * r];
    #pragma unroll
    for (int r = 0; r < 4; ++r)
      #pragma unroll
      for (int s = 0; s < 4; ++s) {
        acc[r][s] = dot2a(d4[r].x, h4[s].x, acc[r][s]);
        acc[r][s] = dot2a(d4[r].y, h4[s].y, acc[r][s]);
        acc[r][s] = dot2a(d4[r].z, h4[s].z, acc[r][s]);
        acc[r][s] = dot2a(d4[r].w, h4[s].w, acc[r][s]);
      }
  }
  #pragma unroll
  for (int r = 0; r < 4; ++r) {
    const float db = decb[oq + 32 * r];
    #pragma unroll
    for (int s = 0; s < 4; ++s) {
      const size_t g = r0 + tq + 16 * s;
      out[((size_t)t0 * BB + g) * OO + oq + 32 * r] = sanz(acc[r][s] + db);
    }
  }
  if (t0 == 0 && blockIdx.x == 0 && tid == 0) mk[3] = MAGIC;
}

// ---- k_probe ----
extern "C" __global__ void k_probe(const float* __restrict__ mk, float* __restrict__ out,
                                   int wsTooSmall) {
  if (wsTooSmall)     { out[0] = 100000.f; return; }
  if (mk[0] != MAGIC) { out[0] = 200000.f; return; }
  if (mk[1] != MAGIC) { out[0] = 300000.f; return; }
  if (mk[2] != MAGIC) { out[0] = 400000.f; return; }
  if (mk[3] != MAGIC) { out[0] = 500000.f; return; }
  if (mk[5] == 7.f)   { out[0] = 600000.f; return; }
  if (mk[4] == 7.f)   { out[0] = 700000.f; return; }
}

extern "C" void kernel_launch(void* const* d_in, const int* in_sizes, int n_in,
                              void* d_out, int out_size, void* d_ws, size_t ws_size,
                              hipStream_t stream) {
  (void)in_sizes; (void)n_in; (void)out_size;
  const int* idx = (const int*)d_in[0];
  const float* emb = (const float*)d_in[1];
  const float* wxh = (const float*)d_in[2];
  const float* bxh = (const float*)d_in[3];
  const float* whh = (const float*)d_in[4];
  const float* bhh = (const float*)d_in[5];
  const float* dw  = (const float*)d_in[6];
  const float* db  = (const float*)d_in[7];
  float* out = (float*)d_out;

  char* ws = (char*)d_ws;
  float* P = (float*)ws;                                    // @0       256 KB
  float* hstate = (float*)(ws + (256 << 10));               // @256 KB  256 KB
  float* mk = (float*)(ws + (512 << 10));                   // @512 KB    4 KB
  unsigned int* wpack = (unsigned int*)(ws + (516 << 10));  // @516 KB  512 KB
  uint4* decP4 = (uint4*)(ws + (1076 << 10));               // @1076 KB 128 KB
  unsigned short* ring16 = (unsigned short*)(ws + (1204 << 10));  // @1204 KB

  int chunkT = 0;
  const int opts[8] = {2048, 1024, 768, 512, 256, 128, 32, 8};
  for (int i = 0; i < 8; ++i) {
    const size_t need = (size_t)(1204 << 10) + (size_t)opts[i] * BB * HH * 2;
    if (ws_size >= need) { chunkT = opts[i]; break; }
  }
  if (chunkT == 0) {
    k_probe<<<1, 1, 0, stream>>>(nullptr, out, 1);
    return;
  }

  const int ldsRec = NLDG * 512 * 16 + 2048;  // 149,504 B
  const int ldsDec = 64 * 64 * 16;            //  65,536 B
  (void)hipFuncSetAttribute(reinterpret_cast<const void*>(k_rec),
                            hipFuncAttributeMaxDynamicSharedMemorySize, ldsRec);
  (void)hipFuncSetAttribute(reinterpret_cast<const void*>(k_dec),
                            hipFuncAttributeMaxDynamicSharedMemorySize, ldsDec);

  k_init<<<1, 64, 0, stream>>>(mk);
  k_pre<<<128, 512, 0, stream>>>(emb, wxh, bxh, bhh, P, mk);
  k_pack<<<512, 256, 0, stream>>>(whh, wpack);
  k_packd<<<32, 256, 0, stream>>>(dw, decP4);
  bool first = true;
  for (int t0 = 0; t0 < TT; t0 += chunkT) {
    k_rec<<<BB, 512, ldsRec, stream>>>(idx, P, wpack, hstate, ring16, mk, t0, chunkT);
    if (first) {
      k_chk<<<1, 512, 0, stream>>>(idx, P, wpack, ring16, mk);
      first = false;
    }
    k_dec<<<chunkT * 2, 512, ldsDec, stream>>>((const uint4*)ring16, decP4, db, out, mk, t0);
  }
  k_probe<<<1, 1, 0, stream>>>(mk, out, 0);
}